// Round 1
// baseline (432.814 us; speedup 1.0000x reference)
//
#include <hip/hip_runtime.h>
#include <stdint.h>

#define M_DIM 8192
#define N_DIM 8192
#define K_DIM 64
#define BM 64
#define BN 256
#define ZSTR 72    // 64 + 8 bf16 pad -> 144B rows: 8-way on b128 (HW minimum), 16B aligned
#define ESTR 260   // epilogue f32 stride (+4 pad): scatter 2-way (free), read 8-way (b128 min)

typedef __attribute__((ext_vector_type(8))) short short8;   // 8 bf16 = 4 VGPRs
typedef __attribute__((ext_vector_type(4))) float f32x4;

__device__ __forceinline__ ushort f2bf(float f) {
    // round-to-nearest-even fp32 -> bf16 (inputs finite)
    uint u = __float_as_uint(f);
    return (ushort)((u + 0x7FFFu + ((u >> 16) & 1u)) >> 16);
}

// Single fused kernel: no workspace, no prep dispatches.
// Block = 256 threads = 4 waves; tile 64(M) x 256(N). Wave wv owns cols
// [wv*64, wv*64+64). z tile (fp32, L2-resident 2MB) is converted+transposed
// into LDS per block; y fragments converted fp32->bf16 in-register.
// Verified MFMA layouts (R1, absmax 0.25):
//   A: lane l holds A[m=l&15][k=(l>>4)*8+j]
//   B: lane l holds B[k=(l>>4)*8+j][n=l&15]
//   C: col=l&15, row=(l>>4)*4+reg
__global__ __launch_bounds__(256) void sddmm_fused(const float* __restrict__ x,
                                                   const float* __restrict__ y,
                                                   const float* __restrict__ z,
                                                   float* __restrict__ out) {
    // Overlaid LDS: phase 1 = zt tile (bf16, 256 rows x ZSTR = 36,864 B),
    // phase 2 = epilogue re-layout (f32, 32 rows x ESTR = 33,280 B).
    __shared__ __align__(16) char smem[BN * ZSTR * 2];
    ushort* zt  = (ushort*)smem;
    float*  eld = (float*)smem;

    const int tid = threadIdx.x;
    const int wv  = tid >> 6;   // wave 0..3
    const int l   = tid & 63;
    const int q   = l >> 4;     // 0..3
    const int r16 = l & 15;     // 0..15
    const int m0  = blockIdx.y * BM;
    const int n0  = blockIdx.x * BN;

    // ---- x prefetch, rows m0..m0+31 (HBM latency hides under staging+MFMA;
    //      we sit in the 129-256 VGPR band regardless, so this is free) ----
    const size_t base0 = (size_t)(m0 + wv) * N_DIM + n0 + 4 * l;
    f32x4 xv[8];
#pragma unroll
    for (int p = 0; p < 8; ++p)
        xv[p] = *(const f32x4*)(x + base0 + (size_t)(4 * p) * N_DIM);

    // ---- stage z[:, n0+tid] -> zt row tid (bf16, k-contiguous) ----
    // Global reads: per-wave 256B coalesced per k-row, all L2 hits after warmup
    // (z = 2 MB total, fits every XCD's 4 MB L2).
    {
        const float* zc = z + n0 + tid;
        uint pk[32];
#pragma unroll
        for (int kp = 0; kp < 32; ++kp) {
            float z0 = zc[(size_t)(2 * kp) * N_DIM];
            float z1 = zc[(size_t)(2 * kp + 1) * N_DIM];
            pk[kp] = (uint)f2bf(z0) | ((uint)f2bf(z1) << 16);
        }
        uint4* dst = (uint4*)(zt + (size_t)tid * ZSTR);
#pragma unroll
        for (int i = 0; i < 8; ++i)
            dst[i] = make_uint4(pk[4 * i], pk[4 * i + 1], pk[4 * i + 2], pk[4 * i + 3]);
    }

    // ---- A fragments straight from y (fp32 -> bf16 in-register; k-contiguous) ----
    short8 a[4][2];
#pragma unroll
    for (int mi = 0; mi < 4; ++mi)
#pragma unroll
        for (int kc = 0; kc < 2; ++kc) {
            const float* yp = y + (size_t)(m0 + 16 * mi + r16) * K_DIM + 32 * kc + 8 * q;
            float4 v0 = *(const float4*)(yp);
            float4 v1 = *(const float4*)(yp + 4);
            union { uint u[4]; short8 s; } fr;
            fr.u[0] = (uint)f2bf(v0.x) | ((uint)f2bf(v0.y) << 16);
            fr.u[1] = (uint)f2bf(v0.z) | ((uint)f2bf(v0.w) << 16);
            fr.u[2] = (uint)f2bf(v1.x) | ((uint)f2bf(v1.y) << 16);
            fr.u[3] = (uint)f2bf(v1.z) | ((uint)f2bf(v1.w) << 16);
            a[mi][kc] = fr.s;
        }

    __syncthreads();

    // ---- B fragments from LDS + 32 MFMAs ----
    f32x4 acc[4][4] = {};
#pragma unroll
    for (int kc = 0; kc < 2; ++kc) {
        short8 b[4];
#pragma unroll
        for (int ni = 0; ni < 4; ++ni)
            b[ni] = *(const short8*)(zt + (size_t)(wv * 64 + 16 * ni + r16) * ZSTR + 32 * kc + 8 * q);
#pragma unroll
        for (int mi = 0; mi < 4; ++mi)
#pragma unroll
            for (int ni = 0; ni < 4; ++ni)
                acc[mi][ni] = __builtin_amdgcn_mfma_f32_16x16x32_bf16(
                    a[mi][kc], b[ni], acc[mi][ni], 0, 0, 0);
    }

    __syncthreads();   // all zt reads done -> smem reusable for epilogue

    // ---- epilogue half 0: rows m0..m0+31 ----
#pragma unroll
    for (int mi = 0; mi < 2; ++mi)
#pragma unroll
        for (int ni = 0; ni < 4; ++ni)
#pragma unroll
            for (int r = 0; r < 4; ++r)
                eld[(16 * mi + 4 * q + r) * ESTR + wv * 64 + 16 * ni + r16] = acc[mi][ni][r];
    __syncthreads();

    // issue second-half x loads now; latency hides under the pass-0 LDS reads/stores
    const size_t base1 = base0 + (size_t)32 * N_DIM;
    f32x4 xw[8];
#pragma unroll
    for (int p = 0; p < 8; ++p)
        xw[p] = *(const f32x4*)(x + base1 + (size_t)(4 * p) * N_DIM);

#pragma unroll
    for (int p = 0; p < 8; ++p) {
        f32x4 cv = *(const f32x4*)(&eld[(4 * p + wv) * ESTR + 4 * l]);
        *(f32x4*)(out + base0 + (size_t)(4 * p) * N_DIM) = cv * xv[p];
    }
    __syncthreads();

    // ---- epilogue half 1: rows m0+32..m0+63 ----
#pragma unroll
    for (int mi = 0; mi < 2; ++mi)
#pragma unroll
        for (int ni = 0; ni < 4; ++ni)
#pragma unroll
            for (int r = 0; r < 4; ++r)
                eld[(16 * mi + 4 * q + r) * ESTR + wv * 64 + 16 * ni + r16] = acc[2 + mi][ni][r];
    __syncthreads();

#pragma unroll
    for (int p = 0; p < 8; ++p) {
        f32x4 cv = *(const f32x4*)(&eld[(4 * p + wv) * ESTR + 4 * l]);
        *(f32x4*)(out + base1 + (size_t)(4 * p) * N_DIM) = cv * xw[p];
    }
}

extern "C" void kernel_launch(void* const* d_in, const int* in_sizes, int n_in,
                              void* d_out, int out_size, void* d_ws, size_t ws_size,
                              hipStream_t stream) {
    const float* x = (const float*)d_in[0];
    const float* y = (const float*)d_in[1];
    const float* z = (const float*)d_in[2];
    float* out = (float*)d_out;

    // Single dispatch, zero workspace use: the harness's 1 GiB per-iteration
    // workspace re-poison (the ~167 us fills dominating the rocprof table)
    // should leave the timed path, and the 2 prep launches disappear.
    dim3 grid(N_DIM / BN, M_DIM / BM);   // (32, 128)
    sddmm_fused<<<grid, 256, 0, stream>>>(x, y, z, out);
}

// Round 2
// 432.684 us; speedup vs baseline: 1.0003x; 1.0003x over previous
//
#include <hip/hip_runtime.h>
#include <stdint.h>

#define M_DIM 8192
#define N_DIM 8192
#define K_DIM 64
#define BM 64
#define BN 256
#define ZSTR 72    // 64 + 8 bf16 pad -> 144B rows: 8-way on b128 (HW floor), 16B aligned
#define ESTR 260   // epilogue f32 stride (+4 pad): scatter 2-way (free), read = b128 floor

typedef __attribute__((ext_vector_type(8))) short short8;   // 8 bf16 = 4 VGPRs
typedef __attribute__((ext_vector_type(4))) float f32x4;

__device__ __forceinline__ ushort f2bf(float f) {
    // round-to-nearest-even fp32 -> bf16 (inputs finite)
    uint u = __float_as_uint(f);
    return (ushort)((u + 0x7FFFu + ((u >> 16) & 1u)) >> 16);
}

// Single fused kernel, tuned for occupancy: __launch_bounds__(256,4) caps
// VGPR at 128 -> 4 waves/SIMD (4 blocks/CU; LDS 36.9KB*4 = 147.5KB fits).
// Phases: stage z-tile (fp32->bf16 transpose into LDS, 2 chunks) ->
// MFMA with JIT y-fragment conversion -> 2x (scatter acc half to LDS,
// stream x*acc to out). No cross-phase register prefetch arrays.
// Verified MFMA layouts (R1, absmax 0.25):
//   A: lane l holds A[m=l&15][k=(l>>4)*8+j]
//   B: lane l holds B[k=(l>>4)*8+j][n=l&15]
//   C: col=l&15, row=(l>>4)*4+reg
__global__ __launch_bounds__(256, 4) void sddmm_fused(const float* __restrict__ x,
                                                      const float* __restrict__ y,
                                                      const float* __restrict__ z,
                                                      float* __restrict__ out) {
    // Overlaid LDS: phase 1 = zt tile (bf16, 256 rows x ZSTR = 36,864 B),
    // phase 2 = epilogue re-layout (f32, 32 rows x ESTR = 33,280 B).
    __shared__ __align__(16) char smem[BN * ZSTR * 2];
    ushort* zt  = (ushort*)smem;
    float*  eld = (float*)smem;

    const int tid = threadIdx.x;
    const int wv  = tid >> 6;   // wave 0..3
    const int l   = tid & 63;
    const int q   = l >> 4;     // 0..3
    const int r16 = l & 15;     // 0..15
    const int m0  = blockIdx.y * BM;
    const int n0  = blockIdx.x * BN;

    // ---- stage z[:, n0+tid] -> zt row tid (bf16, k-contiguous) ----
    // Two 32-k chunks (#pragma unroll 1) keep staging regs ~50 instead of ~100.
    // Reads: 256B coalesced per wave per k-row, L2-resident (z = 2 MB).
    {
        const float* zc   = z + n0 + tid;
        ushort*      zrow = zt + (size_t)tid * ZSTR;
#pragma unroll 1
        for (int c = 0; c < 2; ++c) {
            uint w[16];
#pragma unroll
            for (int j = 0; j < 16; ++j) {
                float z0 = zc[(size_t)(32 * c + 2 * j) * N_DIM];
                float z1 = zc[(size_t)(32 * c + 2 * j + 1) * N_DIM];
                w[j] = (uint)f2bf(z0) | ((uint)f2bf(z1) << 16);
            }
            uint4* dst = (uint4*)(zrow + 32 * c);
#pragma unroll
            for (int i = 0; i < 4; ++i)
                dst[i] = make_uint4(w[4 * i], w[4 * i + 1], w[4 * i + 2], w[4 * i + 3]);
        }
    }

    __syncthreads();

    // ---- MFMA: B frags from LDS, A frags converted JIT from y (L2-resident) ----
    f32x4 acc[4][4] = {};
#pragma unroll
    for (int kc = 0; kc < 2; ++kc) {
        short8 a[4], b[4];
#pragma unroll
        for (int mi = 0; mi < 4; ++mi) {
            const float* yp = y + (size_t)(m0 + 16 * mi + r16) * K_DIM + 32 * kc + 8 * q;
            float4 v0 = *(const float4*)(yp);
            float4 v1 = *(const float4*)(yp + 4);
            union { uint u[4]; short8 s; } fr;
            fr.u[0] = (uint)f2bf(v0.x) | ((uint)f2bf(v0.y) << 16);
            fr.u[1] = (uint)f2bf(v0.z) | ((uint)f2bf(v0.w) << 16);
            fr.u[2] = (uint)f2bf(v1.x) | ((uint)f2bf(v1.y) << 16);
            fr.u[3] = (uint)f2bf(v1.z) | ((uint)f2bf(v1.w) << 16);
            a[mi] = fr.s;
        }
#pragma unroll
        for (int ni = 0; ni < 4; ++ni)
            b[ni] = *(const short8*)(zt + (size_t)(wv * 64 + 16 * ni + r16) * ZSTR + 32 * kc + 8 * q);
#pragma unroll
        for (int mi = 0; mi < 4; ++mi)
#pragma unroll
            for (int ni = 0; ni < 4; ++ni)
                acc[mi][ni] = __builtin_amdgcn_mfma_f32_16x16x32_bf16(
                    a[mi], b[ni], acc[mi][ni], 0, 0, 0);
    }

    __syncthreads();   // all zt reads done -> smem reusable for epilogue

    // ---- epilogue: two 32-row halves; acc half dies after its scatter ----
#pragma unroll
    for (int h = 0; h < 2; ++h) {
#pragma unroll
        for (int mi = 0; mi < 2; ++mi)
#pragma unroll
            for (int ni = 0; ni < 4; ++ni)
#pragma unroll
                for (int r = 0; r < 4; ++r)
                    eld[(16 * mi + 4 * q + r) * ESTR + wv * 64 + 16 * ni + r16] =
                        acc[2 * h + mi][ni][r];
        __syncthreads();

        // Wave wv streams rows {4p+wv}: 1 KB contiguous per wave-instruction.
        const size_t base = (size_t)(m0 + 32 * h + wv) * N_DIM + n0 + 4 * l;
        f32x4 xv[8];
#pragma unroll
        for (int p = 0; p < 8; ++p)
            xv[p] = __builtin_nontemporal_load((const f32x4*)(x + base + (size_t)(4 * p) * N_DIM));
#pragma unroll
        for (int p = 0; p < 8; ++p) {
            f32x4 cv = *(const f32x4*)(&eld[(4 * p + wv) * ESTR + 4 * l]);
            __builtin_nontemporal_store(cv * xv[p], (f32x4*)(out + base + (size_t)(4 * p) * N_DIM));
        }
        __syncthreads();   // protect eld before next half's scatter
    }
}

extern "C" void kernel_launch(void* const* d_in, const int* in_sizes, int n_in,
                              void* d_out, int out_size, void* d_ws, size_t ws_size,
                              hipStream_t stream) {
    const float* x = (const float*)d_in[0];
    const float* y = (const float*)d_in[1];
    const float* z = (const float*)d_in[2];
    float* out = (float*)d_out;

    dim3 grid(N_DIM / BN, M_DIM / BM);   // (32, 128)
    sddmm_fused<<<grid, 256, 0, stream>>>(x, y, z, out);
}